// Round 3
// baseline (1476.279 us; speedup 1.0000x reference)
//
#include <hip/hip_runtime.h>
#include <hip/hip_bf16.h>
#include <cstdint>
#include <cstddef>

typedef __bf16 bf16_t;
typedef __bf16 bf16x8 __attribute__((ext_vector_type(8)));
typedef float  f32x4  __attribute__((ext_vector_type(4)));

static constexpr int Bsz  = 4;
static constexpr int Nseq = 2048;
static constexpr int Dmod = 1024;
static constexpr int H    = 16;
static constexpr int DH   = 64;
static constexpr int M_TOT = Bsz * Nseq;  // 8192
static constexpr int K    = Dmod;

__device__ __forceinline__ f32x4 mfma16(bf16x8 a, bf16x8 b, f32x4 c) {
  return __builtin_amdgcn_mfma_f32_16x16x32_bf16(a, b, c, 0, 0, 0);
}

__device__ __forceinline__ bf16x8 cvt8(const float* p) {
  f32x4 lo = *(const f32x4*)(p);
  f32x4 hi = *(const f32x4*)(p + 4);
  bf16x8 r;
#pragma unroll
  for (int i = 0; i < 4; ++i) { r[i] = (bf16_t)lo[i]; r[4 + i] = (bf16_t)hi[i]; }
  return r;
}

// C = A (M x K, row-major) * W^T (W is Nout x K, row-major, f32) + bias
// AF32: A is float32, else bf16.  CT: output element type (bf16 or float).
// MODE 0: write head layout   [B,H,N,64]
// MODE 1: write V^T layout    [B,H,64,N]
// MODE 2: write row-major     [M, Nout]
template <int MODE, bool AF32, typename CT>
__global__ __launch_bounds__(256) void gemm_bt(
    const void* __restrict__ Av, const float* __restrict__ W,
    const float* __restrict__ bias, CT* __restrict__ C) {
  const int lane = threadIdx.x & 63;
  const int wave = threadIdx.x >> 6;
  const int row  = lane & 15;   // A-row / B-row within 16-chunk (and C col)
  const int kq   = lane >> 4;   // quad id
  const int m0 = blockIdx.x * 64 + wave * 16;
  const int n0 = blockIdx.y * 64;

  f32x4 acc[4];
#pragma unroll
  for (int c = 0; c < 4; ++c) acc[c] = (f32x4){0.f, 0.f, 0.f, 0.f};

  const float*  Af = (const float*)Av  + (size_t)(m0 + row) * K + kq * 8;
  const bf16_t* Ab = (const bf16_t*)Av + (size_t)(m0 + row) * K + kq * 8;
  const float*  Wp0 = W + (size_t)(n0 + row) * K + kq * 8;

  for (int k0 = 0; k0 < K; k0 += 32) {
    bf16x8 a;
    if (AF32) a = cvt8(Af + k0);
    else      a = *(const bf16x8*)(Ab + k0);
#pragma unroll
    for (int c = 0; c < 4; ++c) {
      bf16x8 b = cvt8(Wp0 + (size_t)c * 16 * K + k0);
      acc[c] = mfma16(a, b, acc[c]);
    }
  }

#pragma unroll
  for (int c = 0; c < 4; ++c) {
    const int o = n0 + c * 16 + row;  // C column = lane&15
    const float bv = (MODE == 2 || !bias) ? 0.f : bias[o];
#pragma unroll
    for (int r = 0; r < 4; ++r) {
      const int m = m0 + kq * 4 + r;  // C row = quad*4 + reg
      const float v = acc[c][r] + bv;
      size_t idx;
      if (MODE == 0) {
        const int b = m >> 11, n = m & 2047;
        const int h = o >> 6, od = o & 63;
        idx = (((size_t)b * H + h) * Nseq + n) * DH + od;
      } else if (MODE == 1) {
        const int b = m >> 11, n = m & 2047;
        const int h = o >> 6, od = o & 63;
        idx = (((size_t)b * H + h) * DH + od) * Nseq + n;
      } else {
        idx = (size_t)m * Dmod + o;
      }
      C[idx] = (CT)v;
    }
  }
}

// Flash attention, causal. Q,K: [B,H,N,64]; VT: [B,H,64,N]; X out: [B,N,D]
__global__ __launch_bounds__(256) void attn_fwd(
    const bf16_t* __restrict__ Q, const bf16_t* __restrict__ Kh,
    const bf16_t* __restrict__ VT, bf16_t* __restrict__ X) {
  const int lane = threadIdx.x & 63;
  const int wave = threadIdx.x >> 6;
  const int bh = blockIdx.x;       // 0..63
  const int qtile = blockIdx.y;    // 0..31
  const int q0 = qtile * 64 + wave * 16;
  const int b = bh >> 4, h = bh & 15;
  const int row = lane & 15, kq = lane >> 4;

  __shared__ __align__(16) bf16_t plds[4][16][40];  // row stride 80B

  const bf16_t* Qb = Q + (size_t)bh * Nseq * DH;
  const bf16_t* Kb = Kh + (size_t)bh * Nseq * DH;
  const bf16_t* Vb = VT + (size_t)bh * DH * Nseq;

  bf16x8 qf[2];
  qf[0] = *(const bf16x8*)(Qb + (size_t)(q0 + row) * DH + kq * 8);
  qf[1] = *(const bf16x8*)(Qb + (size_t)(q0 + row) * DH + 32 + kq * 8);

  f32x4 o_acc[4];
#pragma unroll
  for (int c = 0; c < 4; ++c) o_acc[c] = (f32x4){0.f, 0.f, 0.f, 0.f};
  float m_i[4], l_i[4];
#pragma unroll
  for (int r = 0; r < 4; ++r) { m_i[r] = -1e30f; l_i[r] = 0.f; }

  const int kend = q0 + 16;  // exclusive bound on key index
  for (int k0 = 0; k0 < kend; k0 += 32) {
    // S = Q * K^T  (16 x 32 per wave, two 16-col chunks)
    f32x4 s[2];
#pragma unroll
    for (int c = 0; c < 2; ++c) {
      s[c] = (f32x4){0.f, 0.f, 0.f, 0.f};
      const bf16_t* Kp = Kb + (size_t)(k0 + c * 16 + row) * DH + kq * 8;
      s[c] = mfma16(qf[0], *(const bf16x8*)(Kp), s[c]);
      s[c] = mfma16(qf[1], *(const bf16x8*)(Kp + 32), s[c]);
    }
    // scale + causal mask
    float sv[2][4];
#pragma unroll
    for (int c = 0; c < 2; ++c) {
      const int kg = k0 + c * 16 + row;  // key index (C col = lane&15)
#pragma unroll
      for (int r = 0; r < 4; ++r) {
        const int qg = q0 + kq * 4 + r;
        const float v = s[c][r] * 0.125f;
        sv[c][r] = (kg <= qg) ? v : -1e30f;
      }
    }
    // online softmax: row max / rescale / exp / row sum
    float alpha[4];
#pragma unroll
    for (int r = 0; r < 4; ++r) {
      float rm = fmaxf(sv[0][r], sv[1][r]);
#pragma unroll
      for (int mset = 1; mset < 16; mset <<= 1)
        rm = fmaxf(rm, __shfl_xor(rm, mset, 64));
      const float mnew = fmaxf(m_i[r], rm);
      alpha[r] = __expf(m_i[r] - mnew);
      const float p0 = __expf(sv[0][r] - mnew);
      const float p1 = __expf(sv[1][r] - mnew);
      sv[0][r] = p0; sv[1][r] = p1;
      float rs = p0 + p1;
#pragma unroll
      for (int mset = 1; mset < 16; mset <<= 1)
        rs += __shfl_xor(rs, mset, 64);
      l_i[r] = l_i[r] * alpha[r] + rs;
      m_i[r] = mnew;
    }
    // P (C-layout) -> LDS -> A-fragment layout
#pragma unroll
    for (int c = 0; c < 2; ++c)
#pragma unroll
      for (int r = 0; r < 4; ++r)
        plds[wave][kq * 4 + r][c * 16 + row] = (bf16_t)sv[c][r];
    __asm__ volatile("s_waitcnt lgkmcnt(0)" ::: "memory");
    const bf16x8 pf = *(const bf16x8*)(&plds[wave][row][kq * 8]);
    // rescale O, then O += P * V
#pragma unroll
    for (int ch = 0; ch < 4; ++ch) {
#pragma unroll
      for (int r = 0; r < 4; ++r) o_acc[ch][r] *= alpha[r];
      const bf16_t* Vp = Vb + (size_t)(ch * 16 + row) * Nseq + k0 + kq * 8;
      o_acc[ch] = mfma16(pf, *(const bf16x8*)(Vp), o_acc[ch]);
    }
  }

  // epilogue: X[b, q, h*64 + d] = O / l
#pragma unroll
  for (int ch = 0; ch < 4; ++ch) {
#pragma unroll
    for (int r = 0; r < 4; ++r) {
      const int qg = q0 + kq * 4 + r;
      const float v = o_acc[ch][r] / l_i[r];
      const size_t idx =
          ((size_t)b * Nseq + qg) * Dmod + h * DH + ch * 16 + row;
      X[idx] = (bf16_t)v;
    }
  }
}

extern "C" void kernel_launch(void* const* d_in, const int* in_sizes, int n_in,
                              void* d_out, int out_size, void* d_ws,
                              size_t ws_size, hipStream_t stream) {
  const float* q  = (const float*)d_in[0];
  const float* k  = (const float*)d_in[1];
  const float* v  = (const float*)d_in[2];
  const float* Wq = (const float*)d_in[3];
  const float* bq = (const float*)d_in[4];
  const float* Wk = (const float*)d_in[5];
  const float* bk = (const float*)d_in[6];
  const float* Wv = (const float*)d_in[7];
  const float* bv = (const float*)d_in[8];
  const float* Wo = (const float*)d_in[9];
  float* out = (float*)d_out;  // reference output dtype = float32

  const size_t elems = (size_t)M_TOT * Dmod;  // 8192*1024
  bf16_t* Qh = (bf16_t*)d_ws;
  bf16_t* Kh = Qh + elems;
  bf16_t* VT = Kh + elems;
  bf16_t* X  = VT + elems;

  dim3 blk(256);
  dim3 gg(M_TOT / 64, Dmod / 64);  // 128 x 16
  gemm_bt<0, true,  bf16_t><<<gg, blk, 0, stream>>>(q, Wq, bq, Qh);
  gemm_bt<0, true,  bf16_t><<<gg, blk, 0, stream>>>(k, Wk, bk, Kh);
  gemm_bt<1, true,  bf16_t><<<gg, blk, 0, stream>>>(v, Wv, bv, VT);

  dim3 ga(Bsz * H, Nseq / 64);  // 64 x 32
  attn_fwd<<<ga, blk, 0, stream>>>(Qh, Kh, VT, X);

  gemm_bt<2, false, float><<<gg, blk, 0, stream>>>(X, Wo, nullptr, out);
}

// Round 5
// 529.856 us; speedup vs baseline: 2.7862x; 2.7862x over previous
//
#include <hip/hip_runtime.h>
#include <hip/hip_bf16.h>
#include <cstdint>
#include <cstddef>

typedef __bf16 bf16_t;
typedef __bf16 bf16x8 __attribute__((ext_vector_type(8)));
typedef float  f32x4  __attribute__((ext_vector_type(4)));

static constexpr int Bsz  = 4;
static constexpr int Nseq = 2048;
static constexpr int Dmod = 1024;
static constexpr int H    = 16;
static constexpr int DH   = 64;
static constexpr int M_TOT = Bsz * Nseq;  // 8192
static constexpr int K    = Dmod;
static constexpr int BM = 128, BN = 128, BK = 32;

__device__ __forceinline__ f32x4 mfma16(bf16x8 a, bf16x8 b, f32x4 c) {
  return __builtin_amdgcn_mfma_f32_16x16x32_bf16(a, b, c, 0, 0, 0);
}

__device__ __forceinline__ bf16x8 cvt8(const float* p) {
  f32x4 lo = *(const f32x4*)(p);
  f32x4 hi = *(const f32x4*)(p + 4);
  bf16x8 r;
#pragma unroll
  for (int i = 0; i < 4; ++i) { r[i] = (bf16_t)lo[i]; r[4 + i] = (bf16_t)hi[i]; }
  return r;
}

// async global->LDS, 16B per lane. LDS dest = wave-uniform base + lane*16.
__device__ __forceinline__ void async16(const bf16_t* g, bf16_t* l) {
  __builtin_amdgcn_global_load_lds(
      (const __attribute__((address_space(1))) void*)g,
      (__attribute__((address_space(3))) void*)l, 16, 0, 0);
}

// ---------------- f32 -> bf16 conversion pass ----------------
struct CvtArgs {
  const float* src[7];
  bf16_t* dst[7];
  int n[7];
};

__global__ __launch_bounds__(256) void cvt_kernel(CvtArgs a) {
  const int z = blockIdx.y;
  const float* s = a.src[z];
  bf16x8* d = (bf16x8*)a.dst[z];
  const int n8 = a.n[z] >> 3;
  const int stride = gridDim.x * 256;
  for (int i = blockIdx.x * 256 + threadIdx.x; i < n8; i += stride)
    d[i] = cvt8(s + (size_t)i * 8);
}

// ---------------- tiled bf16 GEMM: C = A * W^T ----------------
// A: M x K row-major bf16; W: Nout x K row-major bf16.
// MODE 0: write head layout [B,H,N,64] (+bias)
// MODE 1: write V^T layout  [B,H,64,N] (+bias)
// MODE 2: write row-major   [M, 1024] as float (no bias)
template <int MODE, typename CT>
__global__ __launch_bounds__(256) void gemm_tile(
    const bf16_t* __restrict__ A, const bf16_t* __restrict__ W,
    const float* __restrict__ bias, CT* __restrict__ C) {
  __shared__ bf16_t As[BM][BK];  // 8 KB
  __shared__ bf16_t Ws[BN][BK];  // 8 KB
  const int tid  = threadIdx.x;
  const int lane = tid & 63;
  const int wave = tid >> 6;           // 0..3
  const int wm = wave & 1, wn = wave >> 1;  // 2x2 wave grid, 64x64 each
  const int row = lane & 15, quad = lane >> 4;

  const int m_blk = blockIdx.x * BM;
  const int n_blk = blockIdx.y * BN;

  f32x4 acc[4][4];
#pragma unroll
  for (int i = 0; i < 4; ++i)
#pragma unroll
    for (int j = 0; j < 4; ++j) acc[i][j] = (f32x4){0.f, 0.f, 0.f, 0.f};

  // staging: 8 segments of 16 rows; wave w handles segs {2w, 2w+1}
  const int srow = lane >> 2;        // 0..15
  const int scol = (lane & 3) * 8;   // element col 0,8,16,24

  const bf16_t* Abase = A + (size_t)m_blk * K + scol;
  const bf16_t* Wbase = W + (size_t)n_blk * K + scol;

  for (int k0 = 0; k0 < K; k0 += BK) {
#pragma unroll
    for (int j = 0; j < 2; ++j) {
      const int seg = wave * 2 + j;
      async16(Abase + (size_t)(seg * 16 + srow) * K + k0, &As[seg * 16][0]);
      async16(Wbase + (size_t)(seg * 16 + srow) * K + k0, &Ws[seg * 16][0]);
    }
    __syncthreads();  // drains vmcnt before barrier (compiler-inserted)

    bf16x8 af[4], wf[4];
#pragma unroll
    for (int i = 0; i < 4; ++i)
      af[i] = *(const bf16x8*)(&As[wm * 64 + i * 16 + row][quad * 8]);
#pragma unroll
    for (int i = 0; i < 4; ++i)
      wf[i] = *(const bf16x8*)(&Ws[wn * 64 + i * 16 + row][quad * 8]);
#pragma unroll
    for (int i = 0; i < 4; ++i)
#pragma unroll
      for (int j = 0; j < 4; ++j)
        acc[i][j] = mfma16(af[i], wf[j], acc[i][j]);
    __syncthreads();
  }

  // epilogue: C row = quad*4 + r, C col = row  (m89/m91 verified layout)
#pragma unroll
  for (int j = 0; j < 4; ++j) {
    const int o = n_blk + wn * 64 + j * 16 + row;
    const float bv = (MODE == 2) ? 0.f : bias[o];
#pragma unroll
    for (int i = 0; i < 4; ++i) {
#pragma unroll
      for (int r = 0; r < 4; ++r) {
        const int m = m_blk + wm * 64 + i * 16 + quad * 4 + r;
        const float v = acc[i][j][r] + bv;
        size_t idx;
        if (MODE == 0) {
          const int b = m >> 11, n = m & 2047;
          const int h = o >> 6, od = o & 63;
          idx = (((size_t)b * H + h) * Nseq + n) * DH + od;
        } else if (MODE == 1) {
          const int b = m >> 11, n = m & 2047;
          const int h = o >> 6, od = o & 63;
          idx = (((size_t)b * H + h) * DH + od) * Nseq + n;
        } else {
          idx = (size_t)m * Dmod + o;
        }
        C[idx] = (CT)v;
      }
    }
  }
}

// ---------------- flash attention (unchanged from R3) ----------------
__global__ __launch_bounds__(256) void attn_fwd(
    const bf16_t* __restrict__ Q, const bf16_t* __restrict__ Kh,
    const bf16_t* __restrict__ VT, bf16_t* __restrict__ X) {
  const int lane = threadIdx.x & 63;
  const int wave = threadIdx.x >> 6;
  const int bh = blockIdx.x;
  const int qtile = blockIdx.y;
  const int q0 = qtile * 64 + wave * 16;
  const int b = bh >> 4, h = bh & 15;
  const int row = lane & 15, kq = lane >> 4;

  __shared__ __align__(16) bf16_t plds[4][16][40];

  const bf16_t* Qb = Q + (size_t)bh * Nseq * DH;
  const bf16_t* Kb = Kh + (size_t)bh * Nseq * DH;
  const bf16_t* Vb = VT + (size_t)bh * DH * Nseq;

  bf16x8 qf[2];
  qf[0] = *(const bf16x8*)(Qb + (size_t)(q0 + row) * DH + kq * 8);
  qf[1] = *(const bf16x8*)(Qb + (size_t)(q0 + row) * DH + 32 + kq * 8);

  f32x4 o_acc[4];
#pragma unroll
  for (int c = 0; c < 4; ++c) o_acc[c] = (f32x4){0.f, 0.f, 0.f, 0.f};
  float m_i[4], l_i[4];
#pragma unroll
  for (int r = 0; r < 4; ++r) { m_i[r] = -1e30f; l_i[r] = 0.f; }

  const int kend = q0 + 16;
  for (int k0 = 0; k0 < kend; k0 += 32) {
    f32x4 s[2];
#pragma unroll
    for (int c = 0; c < 2; ++c) {
      s[c] = (f32x4){0.f, 0.f, 0.f, 0.f};
      const bf16_t* Kp = Kb + (size_t)(k0 + c * 16 + row) * DH + kq * 8;
      s[c] = mfma16(qf[0], *(const bf16x8*)(Kp), s[c]);
      s[c] = mfma16(qf[1], *(const bf16x8*)(Kp + 32), s[c]);
    }
    float sv[2][4];
#pragma unroll
    for (int c = 0; c < 2; ++c) {
      const int kg = k0 + c * 16 + row;
#pragma unroll
      for (int r = 0; r < 4; ++r) {
        const int qg = q0 + kq * 4 + r;
        const float v = s[c][r] * 0.125f;
        sv[c][r] = (kg <= qg) ? v : -1e30f;
      }
    }
    float alpha[4];
#pragma unroll
    for (int r = 0; r < 4; ++r) {
      float rm = fmaxf(sv[0][r], sv[1][r]);
#pragma unroll
      for (int mset = 1; mset < 16; mset <<= 1)
        rm = fmaxf(rm, __shfl_xor(rm, mset, 64));
      const float mnew = fmaxf(m_i[r], rm);
      alpha[r] = __expf(m_i[r] - mnew);
      const float p0 = __expf(sv[0][r] - mnew);
      const float p1 = __expf(sv[1][r] - mnew);
      sv[0][r] = p0; sv[1][r] = p1;
      float rs = p0 + p1;
#pragma unroll
      for (int mset = 1; mset < 16; mset <<= 1)
        rs += __shfl_xor(rs, mset, 64);
      l_i[r] = l_i[r] * alpha[r] + rs;
      m_i[r] = mnew;
    }
#pragma unroll
    for (int c = 0; c < 2; ++c)
#pragma unroll
      for (int r = 0; r < 4; ++r)
        plds[wave][kq * 4 + r][c * 16 + row] = (bf16_t)sv[c][r];
    __asm__ volatile("s_waitcnt lgkmcnt(0)" ::: "memory");
    const bf16x8 pf = *(const bf16x8*)(&plds[wave][row][kq * 8]);
#pragma unroll
    for (int ch = 0; ch < 4; ++ch) {
#pragma unroll
      for (int r = 0; r < 4; ++r) o_acc[ch][r] *= alpha[r];
      const bf16_t* Vp = Vb + (size_t)(ch * 16 + row) * Nseq + k0 + kq * 8;
      o_acc[ch] = mfma16(pf, *(const bf16x8*)(Vp), o_acc[ch]);
    }
  }

#pragma unroll
  for (int ch = 0; ch < 4; ++ch) {
#pragma unroll
    for (int r = 0; r < 4; ++r) {
      const int qg = q0 + kq * 4 + r;
      const float v = o_acc[ch][r] / l_i[r];
      const size_t idx =
          ((size_t)b * Nseq + qg) * Dmod + h * DH + ch * 16 + row;
      X[idx] = (bf16_t)v;
    }
  }
}

extern "C" void kernel_launch(void* const* d_in, const int* in_sizes, int n_in,
                              void* d_out, int out_size, void* d_ws,
                              size_t ws_size, hipStream_t stream) {
  const float* q  = (const float*)d_in[0];
  const float* k  = (const float*)d_in[1];
  const float* v  = (const float*)d_in[2];
  const float* Wq = (const float*)d_in[3];
  const float* bq = (const float*)d_in[4];
  const float* Wk = (const float*)d_in[5];
  const float* bk = (const float*)d_in[6];
  const float* Wv = (const float*)d_in[7];
  const float* bv = (const float*)d_in[8];
  const float* Wo = (const float*)d_in[9];
  float* out = (float*)d_out;

  const size_t E  = (size_t)M_TOT * Dmod;   // 8M elems
  const size_t EW = (size_t)Dmod * Dmod;    // 1M elems
  bf16_t* ws = (bf16_t*)d_ws;
  bf16_t* qb  = ws;
  bf16_t* kb  = ws + E;
  bf16_t* vb  = ws + 2 * E;
  bf16_t* Wqb = ws + 3 * E;
  bf16_t* Wkb = Wqb + EW;
  bf16_t* Wvb = Wkb + EW;
  bf16_t* Wob = Wvb + EW;
  bf16_t* Qh  = Wob + EW;
  bf16_t* Kh  = Qh + E;
  bf16_t* VT  = Kh + E;
  bf16_t* X   = kb;  // kb dead after K projection; reuse for attn output

  CvtArgs ca;
  ca.src[0] = q;  ca.dst[0] = qb;  ca.n[0] = (int)E;
  ca.src[1] = k;  ca.dst[1] = kb;  ca.n[1] = (int)E;
  ca.src[2] = v;  ca.dst[2] = vb;  ca.n[2] = (int)E;
  ca.src[3] = Wq; ca.dst[3] = Wqb; ca.n[3] = (int)EW;
  ca.src[4] = Wk; ca.dst[4] = Wkb; ca.n[4] = (int)EW;
  ca.src[5] = Wv; ca.dst[5] = Wvb; ca.n[5] = (int)EW;
  ca.src[6] = Wo; ca.dst[6] = Wob; ca.n[6] = (int)EW;
  cvt_kernel<<<dim3(512, 7), 256, 0, stream>>>(ca);

  dim3 blk(256);
  dim3 gg(M_TOT / BM, Dmod / BN);  // 64 x 8
  gemm_tile<0, bf16_t><<<gg, blk, 0, stream>>>(qb, Wqb, bq, Qh);
  gemm_tile<0, bf16_t><<<gg, blk, 0, stream>>>(kb, Wkb, bk, Kh);
  gemm_tile<1, bf16_t><<<gg, blk, 0, stream>>>(vb, Wvb, bv, VT);

  dim3 ga(Bsz * H, Nseq / 64);  // 64 x 32
  attn_fwd<<<ga, blk, 0, stream>>>(Qh, Kh, VT, X);

  gemm_tile<2, float><<<gg, blk, 0, stream>>>(X, Wob, nullptr, out);
}